// Round 1
// baseline (1490.284 us; speedup 1.0000x reference)
//
#include <hip/hip_runtime.h>
#include <cstdint>

#define B_    16
#define D_    64
#define N_    2304
#define DIN_  66
#define DI_   128
#define QSZ_  ((size_t)B_ * N_ * DI_)
#define SCALE_ 0.08838834764831845f   // 1/sqrt(128)

// ---------------------------------------------------------------------------
// Kernel 1: augmented projection.  x:[B][64][2304]; W*:[128][66]
//   e-row(n) = { x[b][0..63][n], fx(n/48), fy(n%48) }
//   Q,K stored [B][N][128] (row-major);  V stored transposed [B][128][N]
//   (transposed V gives coalesced, conflict-free staging in pass 3).
// thread <-> n ; W reads are wave-uniform (cache-friendly); e split 4 ways.
// ---------------------------------------------------------------------------
__global__ __launch_bounds__(256) void qkv_kernel(
    const float* __restrict__ x,
    const float* __restrict__ Wq, const float* __restrict__ Wk,
    const float* __restrict__ Wv,
    float* __restrict__ Q, float* __restrict__ K, float* __restrict__ Vt)
{
    const int blk = blockIdx.x;          // 16*36 blocks
    const int b  = blk / 36;
    const int nt = blk - b * 36;
    const int t  = threadIdx.x;
    const int nl = t & 63;
    const int eg = t >> 6;               // 0..3 -> e-range of 32
    const int n  = nt * 64 + nl;

    float ereg[DIN_];
    const float* xb = x + (size_t)b * D_ * N_ + n;
#pragma unroll
    for (int d = 0; d < D_; ++d) ereg[d] = xb[(size_t)d * N_];
    const int ix = n / 48, iy = n - ix * 48;
    ereg[64] = -1.0f + ((float)ix + 0.5f) * (2.0f / 48.0f);
    ereg[65] = -1.0f + ((float)iy + 0.5f) * (2.0f / 48.0f);

    const size_t obase = ((size_t)b * N_ + n) * DI_;
    const int e0 = eg * 32;
    for (int ee = 0; ee < 32; ++ee) {
        const int e = e0 + ee;
        const float* wq = Wq + e * DIN_;
        const float* wk = Wk + e * DIN_;
        const float* wv = Wv + e * DIN_;
        float aq = 0.f, ak = 0.f, av = 0.f;
#pragma unroll
        for (int d = 0; d < DIN_; ++d) {
            const float f = ereg[d];
            aq = fmaf(f, wq[d], aq);
            ak = fmaf(f, wk[d], ak);
            av = fmaf(f, wv[d], av);
        }
        Q[obase + e] = aq;
        K[obase + e] = ak;
        Vt[((size_t)b * DI_ + e) * N_ + n] = av;
    }
}

// ---------------------------------------------------------------------------
// Kernel 2: Zr[b][k] = 1 / sum_q exp(SCALE * dot(Q[q],K[k]))
// grid (16 k-tiles x 16 batches) = 256 blocks -> exactly 1 block/CU.
// Block: k-tile of 144 resident in LDS (full e); loops 18 q-tiles of 128,
// Q staged in two e-halves.  Thread tile 8q x 9k, float4 LDS reads (2-way).
// ---------------------------------------------------------------------------
__global__ __launch_bounds__(256, 1) void zsum_kernel(
    const float* __restrict__ Q, const float* __restrict__ K,
    float* __restrict__ Zr)
{
    __shared__ float smem[144 * 132 + 128 * 68];   // 110,848 B -> 1 block/CU
    float* Ks = smem;                 // [144][132]
    float* Qh = smem + 144 * 132;     // [128][68] (also zbuf at the end)
    const int t  = threadIdx.x;
    const int tx = t & 15, ty = t >> 4;
    const int b  = blockIdx.y;
    const int k0 = blockIdx.x * 144;

    {   // stage K tile [144][128]
        const int r0 = t >> 5, c4 = (t & 31) << 2;
        for (int r = r0; r < 144; r += 8)
            *(float4*)(Ks + r * 132 + c4) =
                *(const float4*)(K + ((size_t)b * N_ + k0 + r) * DI_ + c4);
    }

    float zpart[9];
#pragma unroll
    for (int j = 0; j < 9; ++j) zpart[j] = 0.f;

    for (int qt = 0; qt < 18; ++qt) {
        float acc[8][9];
#pragma unroll
        for (int i = 0; i < 8; ++i)
#pragma unroll
            for (int j = 0; j < 9; ++j) acc[i][j] = 0.f;

        for (int eh = 0; eh < 2; ++eh) {
            __syncthreads();
            {   // stage Q half-tile [128][64]
                const int r0 = t >> 4, c4 = (t & 15) << 2;
                for (int r = r0; r < 128; r += 16)
                    *(float4*)(Qh + r * 68 + c4) =
                        *(const float4*)(Q + ((size_t)b * N_ + qt * 128 + r) * DI_
                                         + eh * 64 + c4);
            }
            __syncthreads();
#pragma unroll 2
            for (int ec = 0; ec < 64; ec += 4) {
                float aq[8][4], bk[9][4];
#pragma unroll
                for (int i = 0; i < 4; ++i) {
                    *(float4*)aq[i]     = *(const float4*)(Qh + (4 * ty + i) * 68 + ec);
                    *(float4*)aq[4 + i] = *(const float4*)(Qh + (64 + 4 * ty + i) * 68 + ec);
                }
#pragma unroll
                for (int j = 0; j < 9; ++j)
                    *(float4*)bk[j] = *(const float4*)(Ks + (9 * tx + j) * 132 + eh * 64 + ec);
#pragma unroll
                for (int i = 0; i < 8; ++i)
#pragma unroll
                    for (int j = 0; j < 9; ++j)
#pragma unroll
                        for (int c = 0; c < 4; ++c)
                            acc[i][j] = fmaf(aq[i][c], bk[j][c], acc[i][j]);
            }
        }
#pragma unroll
        for (int j = 0; j < 9; ++j) {
            float s = 0.f;
#pragma unroll
            for (int i = 0; i < 8; ++i) s += __expf(acc[i][j] * SCALE_);
            zpart[j] += s;
        }
    }

    // reduce over ty (16 partials per k) via LDS (reuse Qh region)
    __syncthreads();
    float* zbuf = Qh;
#pragma unroll
    for (int j = 0; j < 9; ++j) zbuf[ty * 144 + 9 * tx + j] = zpart[j];
    __syncthreads();
    if (t < 144) {
        float s = 0.f;
        for (int r = 0; r < 16; ++r) s += zbuf[r * 144 + t];
        Zr[(size_t)b * N_ + k0 + t] = 1.0f / s;   // store reciprocal
    }
}

// ---------------------------------------------------------------------------
// Kernel 3: Out[b][q][d] = sum_k exp(SCALE*dot(Q[q],K[k])) * V[k][d] * Zr[k]
// grid (16 q-tiles x 16 batches) = 256 blocks -> 1 block/CU.
// Per k-tile of 128: S-phase (e in 2 halves), exp in regs, then PV in two
// k-halves: P -> RA, Z-scaled V half -> RB, accumulate 9q x 8d per thread.
// ---------------------------------------------------------------------------
__global__ __launch_bounds__(256, 1) void attn_out_kernel(
    const float* __restrict__ Q, const float* __restrict__ K,
    const float* __restrict__ Vt, const float* __restrict__ Zr,
    float* __restrict__ Out)
{
    __shared__ float smem[21504];        // 84 KB -> forces 1 block/CU
    float* RA = smem;                    // [144][68]: Q-half, then P
    float* RB = smem + 144 * 68;         // [128][68]: K-half, then V-half
    const int t  = threadIdx.x;
    const int tx = t & 15, ty = t >> 4;
    const int b  = blockIdx.y;
    const int q0 = blockIdx.x * 144;
    const int r0s = t >> 4;              // staging row
    const int c4s = (t & 15) << 2;       // staging col*4

    float acco[9][8];
#pragma unroll
    for (int i = 0; i < 9; ++i)
#pragma unroll
        for (int j = 0; j < 8; ++j) acco[i][j] = 0.f;

    for (int kt = 0; kt < 18; ++kt) {
        const int k0 = kt * 128;
        float s[9][8];
#pragma unroll
        for (int i = 0; i < 9; ++i)
#pragma unroll
            for (int j = 0; j < 8; ++j) s[i][j] = 0.f;

        // ---- S = Q.K^T over e (two halves) ----
        for (int eh = 0; eh < 2; ++eh) {
            __syncthreads();
            for (int r = r0s; r < 144; r += 16)
                *(float4*)(RA + r * 68 + c4s) =
                    *(const float4*)(Q + ((size_t)b * N_ + q0 + r) * DI_ + eh * 64 + c4s);
            for (int r = r0s; r < 128; r += 16)
                *(float4*)(RB + r * 68 + c4s) =
                    *(const float4*)(K + ((size_t)b * N_ + k0 + r) * DI_ + eh * 64 + c4s);
            __syncthreads();
#pragma unroll 2
            for (int ec = 0; ec < 64; ec += 4) {
                float aq[9][4], bk[8][4];
#pragma unroll
                for (int i = 0; i < 9; ++i)
                    *(float4*)aq[i] = *(const float4*)(RA + (9 * ty + i) * 68 + ec);
#pragma unroll
                for (int j = 0; j < 8; ++j)
                    *(float4*)bk[j] = *(const float4*)(RB + (tx + 16 * j) * 68 + ec);
#pragma unroll
                for (int i = 0; i < 9; ++i)
#pragma unroll
                    for (int j = 0; j < 8; ++j)
#pragma unroll
                        for (int c = 0; c < 4; ++c)
                            s[i][j] = fmaf(aq[i][c], bk[j][c], s[i][j]);
            }
        }
        // ---- P = exp(S*scale) in-place ----
#pragma unroll
        for (int i = 0; i < 9; ++i)
#pragma unroll
            for (int j = 0; j < 8; ++j) s[i][j] = __expf(s[i][j] * SCALE_);

        // ---- O += P * (V/Z), k in two halves ----
        for (int kh = 0; kh < 2; ++kh) {
            __syncthreads();
#pragma unroll
            for (int i = 0; i < 9; ++i)
#pragma unroll
                for (int jj = 0; jj < 4; ++jj)
                    RA[(9 * ty + i) * 68 + tx + 16 * jj] = s[i][4 * kh + jj];
            {
                float4 zr4 = *(const float4*)(Zr + (size_t)b * N_ + k0 + kh * 64 + c4s);
                for (int r = r0s; r < 128; r += 16) {
                    float4 v = *(const float4*)(Vt + ((size_t)b * DI_ + r) * N_
                                                + k0 + kh * 64 + c4s);
                    v.x *= zr4.x; v.y *= zr4.y; v.z *= zr4.z; v.w *= zr4.w;
                    *(float4*)(RB + r * 68 + c4s) = v;
                }
            }
            __syncthreads();
#pragma unroll 2
            for (int kc = 0; kc < 64; kc += 4) {
                float ap[9][4], bv[8][4];
#pragma unroll
                for (int i = 0; i < 9; ++i)
                    *(float4*)ap[i] = *(const float4*)(RA + (9 * ty + i) * 68 + kc);
#pragma unroll
                for (int j = 0; j < 8; ++j)
                    *(float4*)bv[j] = *(const float4*)(RB + (tx + 16 * j) * 68 + kc);
#pragma unroll
                for (int i = 0; i < 9; ++i)
#pragma unroll
                    for (int j = 0; j < 8; ++j)
#pragma unroll
                        for (int c = 0; c < 4; ++c)
                            acco[i][j] = fmaf(ap[i][c], bv[j][c], acco[i][j]);
            }
        }
    }

#pragma unroll
    for (int i = 0; i < 9; ++i)
#pragma unroll
        for (int j = 0; j < 8; ++j)
            Out[((size_t)b * N_ + q0 + 9 * ty + i) * DI_ + tx + 16 * j] = acco[i][j];
}

// ---------------------------------------------------------------------------
extern "C" void kernel_launch(void* const* d_in, const int* in_sizes, int n_in,
                              void* d_out, int out_size, void* d_ws, size_t ws_size,
                              hipStream_t stream)
{
    const float* x  = (const float*)d_in[0];
    const float* Wq = (const float*)d_in[1];
    const float* Wk = (const float*)d_in[2];
    const float* Wv = (const float*)d_in[3];

    float* ws = (float*)d_ws;           // needs ~54.2 MiB
    float* Q  = ws;                     // [B][N][DI]
    float* K  = ws + QSZ_;              // [B][N][DI]
    float* Vt = ws + 2 * QSZ_;          // [B][DI][N]
    float* Zr = ws + 3 * QSZ_;          // [B][N] (reciprocal of column sums)
    float* out = (float*)d_out;         // [B][N][DI] f32

    qkv_kernel<<<dim3(B_ * 36), dim3(256), 0, stream>>>(x, Wq, Wk, Wv, Q, K, Vt);
    zsum_kernel<<<dim3(16, B_), dim3(256), 0, stream>>>(Q, K, Zr);
    attn_out_kernel<<<dim3(16, B_), dim3(256), 0, stream>>>(Q, K, Vt, Zr, out);
}

// Round 2
// 215.092 us; speedup vs baseline: 6.9286x; 6.9286x over previous
//
#include <hip/hip_runtime.h>
#include <cstdint>

#define B_    16
#define D_    64
#define N_    2304
#define DI_   128
#define SCALE_ 0.08838834764831845f   // 1/sqrt(128)
#define NB_   ((size_t)B_ * N_ * DI_) // elems per bf16 matrix

typedef __attribute__((ext_vector_type(8)))  short short8v;
typedef __attribute__((ext_vector_type(16))) float f32x16;

__device__ inline unsigned short f2bf(float f) {          // f32 -> bf16 RNE
    unsigned u = __builtin_bit_cast(unsigned, f);
    u = (u + 0x7FFFu + ((u >> 16) & 1u)) >> 16;
    return (unsigned short)u;
}
__device__ inline float bf2f(unsigned short h) {
    unsigned u = ((unsigned)h) << 16;
    return __builtin_bit_cast(float, u);
}
__device__ inline unsigned cvtpk_bf16(float lo, float hi) {
    unsigned r;
    asm volatile("v_cvt_pk_bf16_f32 %0, %1, %2" : "=v"(r) : "v"(lo), "v"(hi));
    return r;
}
// after swap: a = {a.row0, b.row0}, b = {a.row1, b.row1}
__device__ inline void plswap(unsigned &a, unsigned &b) {
    asm volatile("v_permlane32_swap_b32 %0, %1" : "+v"(a), "+v"(b));
}
union U16x8 { int4 v; unsigned short s[8]; };
union F32x8 { float4 v[2]; float f[8]; };

// ---------------------------------------------------------------------------
// Kernel 1: QKV projection via MFMA.  E[n][80] = {x-cols, fx, fy, zeros},
// W3[384][80] = {Wq;Wk;Wv} zero-padded.  Out: Qb/Kb/Vn [B][N][128] bf16.
// grid 16b x 18nt(128), 256 thr (4 waves, wave = 96 out-cols).
// ---------------------------------------------------------------------------
__global__ __launch_bounds__(256) void qkv_kernel(
    const float* __restrict__ x,
    const float* __restrict__ Wq, const float* __restrict__ Wk,
    const float* __restrict__ Wv,
    unsigned short* __restrict__ Qb, unsigned short* __restrict__ Kb,
    unsigned short* __restrict__ Vn)
{
    __shared__ unsigned short Es[128 * 88];
    __shared__ unsigned short Ws[384 * 88];
    const int t = threadIdx.x;
    const int b = blockIdx.x / 18, nt = blockIdx.x - b * 18;
    const int n0 = nt * 128;

    {   // x -> Es transposed bf16 (cols 0..63)
        const int d = t & 63, q4 = t >> 6;
        const float* xp = x + ((size_t)b * D_ + d) * N_ + n0 + q4 * 32;
        float xv[32];
        #pragma unroll
        for (int i = 0; i < 8; ++i) *(float4*)(xv + 4 * i) = *(const float4*)(xp + 4 * i);
        #pragma unroll
        for (int i = 0; i < 32; ++i) Es[(q4 * 32 + i) * 88 + d] = f2bf(xv[i]);
    }
    if (t < 128) {  // coords + zero pad cols 66..79
        int n = n0 + t;
        int ix = n / 48, iy = n - ix * 48;
        Es[t * 88 + 64] = f2bf(-1.0f + ((float)ix + 0.5f) * (2.0f / 48.0f));
        Es[t * 88 + 65] = f2bf(-1.0f + ((float)iy + 0.5f) * (2.0f / 48.0f));
        #pragma unroll
        for (int m = 0; m < 7; ++m) *(unsigned*)&Es[t * 88 + 66 + 2 * m] = 0;
    }
    for (int i = 0; i < 99; ++i) {      // W (3*128*66 = 25344 f32) -> Ws bf16
        int idx = i * 256 + t;
        int r = idx / 66, c = idx - r * 66;
        const float* src = (idx < 8448) ? (Wq + idx)
                         : (idx < 16896) ? (Wk + idx - 8448) : (Wv + idx - 16896);
        Ws[r * 88 + c] = f2bf(*src);
    }
    for (int u = t; u < 384 * 7; u += 256) {   // zero pad W cols 66..79
        int r = u / 7, c = 66 + 2 * (u - r * 7);
        *(unsigned*)&Ws[r * 88 + c] = 0;
    }
    __syncthreads();

    const int l = t & 63, w = t >> 6;
    const int m32 = l & 31, H = l >> 5;
    const int colbase = w * 96;
    #pragma unroll
    for (int nf = 0; nf < 4; ++nf) {
        f32x16 acc[3];
        #pragma unroll
        for (int of = 0; of < 3; ++of)
            #pragma unroll
            for (int i = 0; i < 16; ++i) acc[of][i] = 0.0f;
        #pragma unroll
        for (int kc = 0; kc < 5; ++kc) {
            short8v a = *(const short8v*)&Es[(nf * 32 + m32) * 88 + kc * 16 + H * 8];
            #pragma unroll
            for (int of = 0; of < 3; ++of) {
                short8v bf = *(const short8v*)&Ws[(colbase + of * 32 + m32) * 88 + kc * 16 + H * 8];
                acc[of] = __builtin_amdgcn_mfma_f32_32x32x16_bf16(a, bf, acc[of], 0, 0, 0);
            }
        }
        #pragma unroll
        for (int of = 0; of < 3; ++of) {
            int col0 = colbase + of * 32;
            int mi = col0 >> 7, e0 = col0 & 127;
            unsigned short* dst = (mi == 0) ? Qb : (mi == 1) ? Kb : Vn;
            #pragma unroll
            for (int r = 0; r < 16; ++r) {
                int n = n0 + nf * 32 + (r & 3) + 8 * (r >> 2) + 4 * H;
                dst[((size_t)b * N_ + n) * DI_ + e0 + m32] = f2bf(acc[of][r]);
            }
        }
    }
}

// ---------------------------------------------------------------------------
// Kernel 2: Vn [B][N][128] -> Vt [B][128][N]  (LDS tile transpose)
// ---------------------------------------------------------------------------
__global__ __launch_bounds__(256) void vtrans_kernel(
    const unsigned short* __restrict__ Vn, unsigned short* __restrict__ Vt)
{
    __shared__ unsigned short S[128 * 136];
    const int t = threadIdx.x;
    const int b = blockIdx.x / 18, nt = blockIdx.x - b * 18;
    const int n0 = nt * 128;
    {
        const int n = t >> 1, hf = (t & 1) * 64;
        const unsigned short* src = Vn + ((size_t)b * N_ + n0 + n) * DI_ + hf;
        #pragma unroll
        for (int i = 0; i < 8; ++i)
            *(int4*)&S[n * 136 + hf + i * 8] = *(const int4*)(src + i * 8);
    }
    __syncthreads();
    {
        const int d = t >> 1, nh = (t & 1) * 64;
        unsigned short* dst = Vt + ((size_t)b * DI_ + d) * N_ + n0 + nh;
        #pragma unroll
        for (int g = 0; g < 8; ++g) {
            int4 vv;
            unsigned pk[4];
            #pragma unroll
            for (int j = 0; j < 4; ++j) {
                unsigned short v0 = S[(nh + g * 8 + 2 * j) * 136 + d];
                unsigned short v1 = S[(nh + g * 8 + 2 * j + 1) * 136 + d];
                pk[j] = (unsigned)v0 | ((unsigned)v1 << 16);
            }
            vv.x = pk[0]; vv.y = pk[1]; vv.z = pk[2]; vv.w = pk[3];
            *(int4*)(dst + g * 8) = vv;
        }
    }
}

// ---------------------------------------------------------------------------
// Kernel 3: Zr[b][k] = 1/sum_q exp(SCALE * dot(Q[q],K[k])).
// S^T = K.Q^T via MFMA; K rows in registers (A); Q tiles streamed via LDS (B).
// grid 144 (16b x 9 ktile(256)), 512 thr (8 waves, wave = 32 k-rows).
// ---------------------------------------------------------------------------
__global__ __launch_bounds__(512, 2) void zsum_kernel(
    const unsigned short* __restrict__ Qb, const unsigned short* __restrict__ Kb,
    float* __restrict__ Zr)
{
    __shared__ unsigned short Qs[64 * 128];   // XOR-swizzled, 256B rows
    const int t = threadIdx.x;
    const int blk = blockIdx.x;
    const int b = 2 * (blk & 7) + ((blk >> 3) / 9);   // XCD-local batches
    const int kt = (blk >> 3) % 9;
    const int k0 = kt * 256;
    const int l = t & 63, w = t >> 6;
    const int m32 = l & 31, m15 = l & 15, H = l >> 5;

    short8v kreg[8];   // A-operand: lane holds K[k0+w*32+m32][ec*16+H*8 ..+8]
    {
        const unsigned short* kp = Kb + ((size_t)b * N_ + k0 + w * 32 + m32) * DI_ + H * 8;
        #pragma unroll
        for (int ec = 0; ec < 8; ++ec) kreg[ec] = *(const short8v*)(kp + ec * 16);
    }
    float zacc[16];
    #pragma unroll
    for (int r = 0; r < 16; ++r) zacc[r] = 0.0f;

    const int sq_r = t >> 3, sq_c = (t & 7) * 2;      // staging row / chunk pair
    const unsigned short* qsrc = Qb + (size_t)b * N_ * DI_;
    int4 pf[2];
    #pragma unroll
    for (int j = 0; j < 2; ++j)
        pf[j] = *(const int4*)(qsrc + (size_t)sq_r * DI_ + (sq_c + j) * 8);

    for (int qt = 0; qt < 36; ++qt) {
        #pragma unroll
        for (int j = 0; j < 2; ++j) {
            int c = sq_c + j;
            *(int4*)&Qs[sq_r * 128 + ((c ^ (sq_r & 15)) * 8)] = pf[j];
        }
        __syncthreads();
        if (qt + 1 < 36) {
            #pragma unroll
            for (int j = 0; j < 2; ++j)
                pf[j] = *(const int4*)(qsrc + (size_t)((qt + 1) * 64 + sq_r) * DI_ + (sq_c + j) * 8);
        }
        f32x16 sacc[2];
        #pragma unroll
        for (int qf = 0; qf < 2; ++qf)
            #pragma unroll
            for (int i = 0; i < 16; ++i) sacc[qf][i] = 0.0f;
        #pragma unroll
        for (int ec = 0; ec < 8; ++ec) {
            #pragma unroll
            for (int qf = 0; qf < 2; ++qf) {
                short8v bq = *(const short8v*)&Qs[(qf * 32 + m32) * 128 + ((((ec << 1) | H) ^ m15) * 8)];
                sacc[qf] = __builtin_amdgcn_mfma_f32_32x32x16_bf16(kreg[ec], bq, sacc[qf], 0, 0, 0);
            }
        }
        #pragma unroll
        for (int qf = 0; qf < 2; ++qf)
            #pragma unroll
            for (int r = 0; r < 16; ++r)
                zacc[r] += __expf(sacc[qf][r] * SCALE_);
        __syncthreads();
    }
    #pragma unroll
    for (int r = 0; r < 16; ++r) {
        float v = zacc[r];
        #pragma unroll
        for (int m = 1; m <= 16; m <<= 1) v += __shfl_xor(v, m);
        zacc[r] = v;
    }
    if (m32 == 0) {
        #pragma unroll
        for (int r = 0; r < 16; ++r) {
            int k = k0 + w * 32 + (r & 3) + 8 * (r >> 2) + 4 * H;
            Zr[(size_t)b * N_ + k] = 1.0f / zacc[r];
        }
    }
}

// ---------------------------------------------------------------------------
// Kernel 4: Out[b][q][d] = sum_k exp(SCALE*S[q,k]) * V[k,d] * Zr[k]
// S^T = K.Q^T (Q in regs as B); P stays in registers: cvt_pk_bf16 +
// permlane32_swap builds PV B-fragments; out^T = Vz^T . P.
// Zr folded into V during staging. grid 144 (16b x 9 qtile(256)), 512 thr.
// ---------------------------------------------------------------------------
__global__ __launch_bounds__(512, 2) void attn_kernel(
    const unsigned short* __restrict__ Qb, const unsigned short* __restrict__ Kb,
    const unsigned short* __restrict__ Vt, const float* __restrict__ Zr,
    float* __restrict__ Out)
{
    __shared__ unsigned short Ks[64 * 128];   // [k][e], swizzled
    __shared__ unsigned short Vs[64 * 128];   // [d>>1][(d&1)*64 + k], swizzled
    const int t = threadIdx.x;
    const int blk = blockIdx.x;
    const int b = 2 * (blk & 7) + ((blk >> 3) / 9);
    const int qt = (blk >> 3) % 9;
    const int q0 = qt * 256;
    const int l = t & 63, w = t >> 6;
    const int m32 = l & 31, m15 = l & 15, H = l >> 5;

    short8v qreg[8];   // B-operand: lane holds Q[q0+w*32+m32][ec*16+H*8 ..+8]
    {
        const unsigned short* qp = Qb + ((size_t)b * N_ + q0 + w * 32 + m32) * DI_ + H * 8;
        #pragma unroll
        for (int ec = 0; ec < 8; ++ec) qreg[ec] = *(const short8v*)(qp + ec * 16);
    }
    f32x16 oacc[4];
    #pragma unroll
    for (int df = 0; df < 4; ++df)
        #pragma unroll
        for (int i = 0; i < 16; ++i) oacc[df][i] = 0.0f;

    const int sk_r = t >> 3, sk_c = (t & 7) * 2;   // K staging
    const int sv_d = t >> 2, sv_u = (t & 3) * 2;   // V staging
    const unsigned short* kbase = Kb + (size_t)b * N_ * DI_;
    const unsigned short* vbase = Vt + (size_t)b * DI_ * N_;
    const float* zbase = Zr + (size_t)b * N_;

    int4 kpf[2], vpf[2];
    float4 zpf[2][2];
    #pragma unroll
    for (int j = 0; j < 2; ++j) {
        kpf[j] = *(const int4*)(kbase + (size_t)sk_r * DI_ + (sk_c + j) * 8);
        vpf[j] = *(const int4*)(vbase + (size_t)sv_d * N_ + (sv_u + j) * 8);
        zpf[j][0] = *(const float4*)(zbase + (sv_u + j) * 8);
        zpf[j][1] = *(const float4*)(zbase + (sv_u + j) * 8 + 4);
    }

    for (int kt = 0; kt < 36; ++kt) {
        // write staged tiles (prev compute finished at bottom barrier)
        #pragma unroll
        for (int j = 0; j < 2; ++j) {
            int c = sk_c + j;
            *(int4*)&Ks[sk_r * 128 + ((c ^ (sk_r & 15)) * 8)] = kpf[j];
            U16x8 uin; uin.v = vpf[j];
            F32x8 uz; uz.v[0] = zpf[j][0]; uz.v[1] = zpf[j][1];
            U16x8 uout;
            #pragma unroll
            for (int e = 0; e < 8; ++e) uout.s[e] = f2bf(bf2f(uin.s[e]) * uz.f[e]);
            int vrow = sv_d >> 1;
            int vc = (sv_d & 1) * 8 + sv_u + j;
            *(int4*)&Vs[vrow * 128 + ((vc ^ (vrow & 15)) * 8)] = uout.v;
        }
        __syncthreads();
        if (kt + 1 < 36) {   // async prefetch next tile into regs (T14)
            const int kn = (kt + 1) * 64;
            #pragma unroll
            for (int j = 0; j < 2; ++j) {
                kpf[j] = *(const int4*)(kbase + (size_t)(kn + sk_r) * DI_ + (sk_c + j) * 8);
                vpf[j] = *(const int4*)(vbase + (size_t)sv_d * N_ + kn + (sv_u + j) * 8);
                zpf[j][0] = *(const float4*)(zbase + kn + (sv_u + j) * 8);
                zpf[j][1] = *(const float4*)(zbase + kn + (sv_u + j) * 8 + 4);
            }
        }
        // ---- S^T = K . Q^T ----
        f32x16 sacc[2];
        #pragma unroll
        for (int kf = 0; kf < 2; ++kf)
            #pragma unroll
            for (int i = 0; i < 16; ++i) sacc[kf][i] = 0.0f;
        #pragma unroll
        for (int ec = 0; ec < 8; ++ec) {
            #pragma unroll
            for (int kf = 0; kf < 2; ++kf) {
                short8v ak = *(const short8v*)&Ks[(kf * 32 + m32) * 128 + ((((ec << 1) | H) ^ m15) * 8)];
                sacc[kf] = __builtin_amdgcn_mfma_f32_32x32x16_bf16(ak, qreg[ec], sacc[kf], 0, 0, 0);
            }
        }
        // ---- P = exp, pack bf16, permlane-redistribute, PV ----
        #pragma unroll
        for (int kf = 0; kf < 2; ++kf) {
            float p[16];
            #pragma unroll
            for (int r = 0; r < 16; ++r) p[r] = __expf(sacc[kf][r] * SCALE_);
            unsigned c0[4], c1[4];
            #pragma unroll
            for (int m = 0; m < 4; ++m) {
                c0[m] = cvtpk_bf16(p[4 * m],     p[4 * m + 1]);
                c1[m] = cvtpk_bf16(p[4 * m + 2], p[4 * m + 3]);
            }
            #pragma unroll
            for (int kq = 0; kq < 2; ++kq) {
                unsigned d0 = c0[2 * kq], d2 = c0[2 * kq + 1];
                plswap(d0, d2);
                unsigned d1 = c1[2 * kq], d3 = c1[2 * kq + 1];
                plswap(d1, d3);
                int4 tmp4; tmp4.x = (int)d0; tmp4.y = (int)d1; tmp4.z = (int)d2; tmp4.w = (int)d3;
                short8v pB = __builtin_bit_cast(short8v, tmp4);
                const int kc = kf * 2 + kq;
                #pragma unroll
                for (int df = 0; df < 4; ++df) {
                    int vrow = df * 16 + (m32 >> 1);
                    int vc = (m32 & 1) * 8 + (kc << 1) + H;
                    short8v av = *(const short8v*)&Vs[vrow * 128 + ((vc ^ (vrow & 15)) * 8)];
                    oacc[df] = __builtin_amdgcn_mfma_f32_32x32x16_bf16(av, pB, oacc[df], 0, 0, 0);
                }
            }
        }
        __syncthreads();
    }
    // epilogue: out^T frag -> Out[b][q][d] (L2 merges the 4B stores per line)
    float* outp = Out + ((size_t)b * N_ + q0 + w * 32 + m32) * DI_;
    #pragma unroll
    for (int df = 0; df < 4; ++df)
        #pragma unroll
        for (int r = 0; r < 16; ++r) {
            int d = df * 32 + (r & 3) + 8 * (r >> 2) + 4 * H;
            outp[d] = oacc[df][r];
        }
}

// ---------------------------------------------------------------------------
extern "C" void kernel_launch(void* const* d_in, const int* in_sizes, int n_in,
                              void* d_out, int out_size, void* d_ws, size_t ws_size,
                              hipStream_t stream)
{
    const float* x  = (const float*)d_in[0];
    const float* Wq = (const float*)d_in[1];
    const float* Wk = (const float*)d_in[2];
    const float* Wv = (const float*)d_in[3];

    unsigned short* Qb = (unsigned short*)d_ws;     // [B][N][128] bf16
    unsigned short* Kb = Qb + NB_;                  // [B][N][128] bf16
    unsigned short* Vn = Kb + NB_;                  // [B][N][128] bf16
    unsigned short* Vt = Vn + NB_;                  // [B][128][N] bf16
    float*          Zr = (float*)(Vt + NB_);        // [B][N] f32 (reciprocal)
    float* out = (float*)d_out;

    qkv_kernel  <<<288, 256, 0, stream>>>(x, Wq, Wk, Wv, Qb, Kb, Vn);
    vtrans_kernel<<<288, 256, 0, stream>>>(Vn, Vt);
    zsum_kernel <<<144, 512, 0, stream>>>(Qb, Kb, Zr);
    attn_kernel <<<144, 512, 0, stream>>>(Qb, Kb, Vt, Zr, out);
}